// Round 16
// baseline (94.845 us; speedup 1.0000x reference)
//
#include <hip/hip_runtime.h>
#include <stdint.h>

#define N_ROWS 65536
#define K_CODES 1024
#define DIM 256
#define TILE_STRIDE 2112   // per 16-code tile: 2048 B fp4 frags + 64 B enS

typedef unsigned int uint;

// d_ws layout:
//   [0, 4K)        loss accumulator (first 4B)
//   [4K, +132K)    E4T: fragment-ordered fp4 codebook tiles (+ enS tails)
#define WS_LOSS_OFF  0
#define WS_E4T_OFF   4096

typedef __attribute__((ext_vector_type(4))) float f32x4;
typedef __attribute__((ext_vector_type(4))) int   i32x4;
typedef __attribute__((ext_vector_type(8))) int   i32x8;

// X -> fp8 e4m3 scaled by -16 (negated so MFMA yields enS' - 2x.e directly)
#define XSCALE  (-16.0f)
#define ESCALE4 4096.0f
#define BIAS    16384.0f
#define UNSCALE 3.0517578125e-05f   // 1/32768, exact pow2
#define SCALE1  0x7F7F7F7Fu         // E8M0 identity scales

__device__ __forceinline__ uint pack4_fp8(float a, float b, float c, float d) {
    uint r = 0;
    r = __builtin_amdgcn_cvt_pk_fp8_f32(a, b, r, false);
    r = __builtin_amdgcn_cvt_pk_fp8_f32(c, d, r, true);
    return r;
}
// fp4 e2m1 encode: grid {0,0.5,1,1.5,2,3,4,6}, nearest; input |x|<=4 here
__device__ __forceinline__ uint enc_fp4(float x) {
    float a = fabsf(x);
    uint idx = (a < 0.25f) ? 0u : (a < 0.75f) ? 1u : (a < 1.25f) ? 2u :
               (a < 1.75f) ? 3u : (a < 2.5f)  ? 4u : (a < 3.5f)  ? 5u :
               (a < 5.0f)  ? 6u : 7u;
    return idx | ((x < 0.f) ? 8u : 0u);
}

// ---- prep 1: E -> fragment-ordered fp4 tiles --------------------------------
// One thread per (code, 16B fragment slot): slot j = (ks<<2)|kq holds the
// 32 elements k = ks*128 + kq*32 .. +31 as fp4 nibbles (low nibble = even k).
__global__ __launch_bounds__(256) void vq_prep_pack(const float* __restrict__ E,
                                                    unsigned char* __restrict__ E4T) {
    int id = blockIdx.x * 256 + threadIdx.x;     // 8192 = 1024 codes * 8 slots
    int code = id >> 3, j = id & 7;
    int ks = j >> 2, kq = j & 3;
    const float* src = E + (size_t)code * DIM + ks * 128 + kq * 32;
    uint wds[4];
    #pragma unroll
    for (int q = 0; q < 4; ++q) {
        uint acc = 0;
        #pragma unroll
        for (int e = 0; e < 8; ++e)
            acc |= enc_fp4(src[q * 8 + e] * ESCALE4) << (e * 4);
        wds[q] = acc;
    }
    int t = code >> 4, cl = code & 15;
    i32x4 v = {(int)wds[0], (int)wds[1], (int)wds[2], (int)wds[3]};
    *reinterpret_cast<i32x4*>(
        E4T + (size_t)t * TILE_STRIDE + cl * 128 + ks * 64 + kq * 16) = v;
}

// ---- prep 2: exact fp32 norms (scaled+biased) into tile tails + zero loss --
__global__ __launch_bounds__(64) void vq_prep_norm(const float* __restrict__ E,
                                                   unsigned char* __restrict__ E4T,
                                                   float* __restrict__ lossAcc) {
    int code = blockIdx.x, lane = threadIdx.x;
    if (code == 0 && lane == 0) lossAcc[0] = 0.f;
    float4 v = *reinterpret_cast<const float4*>(E + (size_t)code * DIM + lane * 4);
    float s = v.x * v.x + v.y * v.y + v.z * v.z + v.w * v.w;
    #pragma unroll
    for (int m = 32; m >= 1; m >>= 1) s += __shfl_down(s, m, 64);
    if (lane == 0)
        *reinterpret_cast<float*>(E4T + (size_t)(code >> 4) * TILE_STRIDE
                                  + 2048 + (code & 15) * 4) = s * 32768.0f + BIAS;
}

// ---- fused main: ZERO LDS, ZERO barriers, single-wave blocks ----------------
// Grid 2048 x 64 thr; each wave owns 32 rows (m=2, aF in regs) and sweeps the
// L2-resident 132KB tiled codebook with coalesced global b128 gathers in an
// explicit 4-stage register pipeline (3 groups / 9 loads in flight hides L2
// latency). Waves self-pace -> A/sweep/write phases decorrelate chip-wide.
// MFMA: A = fp8(-16x), B = fp4(4096e) blgp=4, C-init = enS' so
// acc_out = 32768*(||e||^2 - 2x.e) + 16384; u32-packed argmin fold.
__global__ __launch_bounds__(64, 2) void vq_main(const float* __restrict__ X,
                                                 const unsigned char* __restrict__ E4T,
                                                 const float* __restrict__ E,
                                                 float* __restrict__ out,
                                                 float* __restrict__ lossAcc) {
    const int lane = threadIdx.x;
    const int cl = lane & 15;
    const int kq = lane >> 4;
    const int row0 = blockIdx.x * 32;

    // ---- A phase: global -> fp8(-x) regs (m=2, K=128 frags) + x^2 partial --
    i32x8 aF[2][2];
    float xsum = 0.f;
    #pragma unroll
    for (int m = 0; m < 2; ++m) {
        const float* rp = X + (size_t)(row0 + m * 16 + cl) * DIM;
        #pragma unroll
        for (int ks = 0; ks < 2; ++ks) {
            const float* p = rp + ks * 128 + kq * 32;
            uint u[8];
            #pragma unroll
            for (int q = 0; q < 8; ++q) {
                float4 v = *reinterpret_cast<const float4*>(p + q * 4);
                u[q] = pack4_fp8(v.x * XSCALE, v.y * XSCALE,
                                 v.z * XSCALE, v.w * XSCALE);
                xsum = fmaf(v.x, v.x, xsum); xsum = fmaf(v.y, v.y, xsum);
                xsum = fmaf(v.z, v.z, xsum); xsum = fmaf(v.w, v.w, xsum);
            }
            i32x8 f = {(int)u[0], (int)u[1], (int)u[2], (int)u[3],
                       (int)u[4], (int)u[5], (int)u[6], (int)u[7]};
            aF[m][ks] = f;
        }
    }

    uint best[2][4];
    #pragma unroll
    for (int m = 0; m < 2; ++m)
        #pragma unroll
        for (int rr = 0; rr < 4; ++rr) best[m][rr] = 0xFFFFFFFFu;

    // ---- sweep: 64 x 16-code groups, 4-stage register pipeline -------------
    const unsigned char* tb = E4T;       // tile t base = E4T + t*2112
    i32x4 b0[4], b1[4];
    float en[4];

#define ISSUE(S, T) do {                                                     \
        const unsigned char* _p = E4T + (size_t)(T) * TILE_STRIDE;           \
        b0[S] = *reinterpret_cast<const i32x4*>(_p + cl * 128 + kq * 16);    \
        b1[S] = *reinterpret_cast<const i32x4*>(_p + cl * 128 + 64 + kq * 16);\
        en[S] = *reinterpret_cast<const float*>(_p + 2048 + cl * 4);         \
    } while (0)

    ISSUE(0, 0); ISSUE(1, 1); ISSUE(2, 2); ISSUE(3, 3);

    for (int tbase = 0; tbase < 64; tbase += 4) {
        #pragma unroll
        for (int s = 0; s < 4; ++s) {
            const int t = tbase + s;
            f32x4 acc0 = {en[s], en[s], en[s], en[s]};
            f32x4 acc1 = acc0;
            i32x8 f0 = __builtin_shufflevector(b0[s], b0[s], 0, 1, 2, 3, 0, 1, 2, 3);
            i32x8 f1 = __builtin_shufflevector(b1[s], b1[s], 0, 1, 2, 3, 0, 1, 2, 3);
            acc0 = __builtin_amdgcn_mfma_scale_f32_16x16x128_f8f6f4(
                aF[0][0], f0, acc0, 0, 4, 0, SCALE1, 0, SCALE1);
            acc1 = __builtin_amdgcn_mfma_scale_f32_16x16x128_f8f6f4(
                aF[1][0], f0, acc1, 0, 4, 0, SCALE1, 0, SCALE1);
            acc0 = __builtin_amdgcn_mfma_scale_f32_16x16x128_f8f6f4(
                aF[0][1], f1, acc0, 0, 4, 0, SCALE1, 0, SCALE1);
            acc1 = __builtin_amdgcn_mfma_scale_f32_16x16x128_f8f6f4(
                aF[1][1], f1, acc1, 0, 4, 0, SCALE1, 0, SCALE1);

            if (tbase + s + 4 < 64) ISSUE(s, tbase + s + 4);   // refill stage

            // u32-packed fold (codes ascend -> min keeps first occurrence)
            uint codeN = (uint)(t * 16 + cl);
            #pragma unroll
            for (int rr = 0; rr < 4; ++rr) {
                best[0][rr] = min(best[0][rr],
                                  (__float_as_uint(acc0[rr]) & 0xFFFFFC00u) | codeN);
                best[1][rr] = min(best[1][rr],
                                  (__float_as_uint(acc1[rr]) & 0xFFFFFC00u) | codeN);
            }
        }
    }
#undef ISSUE
    (void)tb;

    // ---- wave-local epilogue: butterfly reduce across the 16 cl lanes ------
    // C layout (m89): local row = m*16 + kq*4 + rr, col(code) = cl.
    float minsum = 0.f;
    int bc[2][4];
    #pragma unroll
    for (int m = 0; m < 2; ++m)
        #pragma unroll
        for (int rr = 0; rr < 4; ++rr) {
            uint v = best[m][rr];
            #pragma unroll
            for (int mask = 1; mask < 16; mask <<= 1)
                v = min(v, (uint)__shfl_xor((int)v, mask, 64));
            bc[m][rr] = (int)(v & 1023u);      // per-16-group min (row of its kq)
            if (cl == 0)
                minsum += __uint_as_float(v & 0xFFFFFC00u) - BIAS;
        }

    // loss partial: every thread's x^2 + (cl==0 lanes') scaled min-scores
    float v2 = xsum + ((cl == 0) ? minsum * UNSCALE : 0.f);
    #pragma unroll
    for (int mask = 1; mask < 64; mask <<= 1) v2 += __shfl_xor(v2, mask, 64);
    if (lane == 0) atomicAdd(lossAcc, v2);

    // ---- out[row] = E[bc[row]] (== x + (q-x) to ~3e-7); E is L2-resident ---
    // row i: m = i>>4, kq_src = (i>>2)&3, rr = i&3; broadcast from lane kq*16.
    #pragma unroll 4
    for (int i = 0; i < 32; ++i) {
        int code = __shfl(bc[i >> 4][i & 3], ((i >> 2) & 3) << 4, 64);
        f32x4 q = *reinterpret_cast<const f32x4*>(E + (size_t)code * DIM + lane * 4);
        *reinterpret_cast<f32x4*>(out + (size_t)(row0 + i) * DIM + lane * 4) = q;
    }
}

__global__ void vq_finalize(const float* __restrict__ lossAcc,
                            float* __restrict__ out) {
    out[(size_t)N_ROWS * DIM] = 1.25f * lossAcc[0] / (float)((size_t)N_ROWS * DIM);
}

extern "C" void kernel_launch(void* const* d_in, const int* in_sizes, int n_in,
                              void* d_out, int out_size, void* d_ws, size_t ws_size,
                              hipStream_t stream) {
    const float* X = (const float*)d_in[0];
    const float* E = (const float*)d_in[1];
    float* out = (float*)d_out;

    char* ws = (char*)d_ws;
    float* lossAcc = (float*)(ws + WS_LOSS_OFF);
    unsigned char* E4T = (unsigned char*)(ws + WS_E4T_OFF);

    vq_prep_pack<<<32, 256, 0, stream>>>(E, E4T);
    vq_prep_norm<<<K_CODES, 64, 0, stream>>>(E, E4T, lossAcc);
    vq_main<<<N_ROWS / 32, 64, 0, stream>>>(X, E4T, E, out, lossAcc);
    vq_finalize<<<1, 1, 0, stream>>>(lossAcc, out);
}

// Round 17
// 52.953 us; speedup vs baseline: 1.7911x; 1.7911x over previous
//
#include <hip/hip_runtime.h>
#include <stdint.h>

#define N_ROWS 65536
#define K_CODES 1024
#define DIM 256

typedef unsigned int uint;

// d_ws layout:
//   [0, 4K)       loss accumulator (first 4B)
//   [4K, 8K)      enS[1024]: ||e||^2 * 32768 + 16384 (scaled+biased fp32)
//   [8K, +128K)   E4: fp4(e2m1) codebook scaled x4096, 128B per code
#define WS_LOSS_OFF  0
#define WS_ENS_OFF   4096
#define WS_E4_OFF    8192

typedef __attribute__((ext_vector_type(4))) float f32x4;
typedef __attribute__((ext_vector_type(4))) int   i32x4;
typedef __attribute__((ext_vector_type(8))) int   i32x8;

// X -> fp8 e4m3 scaled by -16 (negated so MFMA yields enS' - 2x.e directly)
#define XSCALE  (-16.0f)
#define ESCALE4 4096.0f
#define BIAS    16384.0f
#define UNSCALE 3.0517578125e-05f   // 1/32768, exact pow2
#define SCALE1  0x7F7F7F7Fu         // E8M0 identity scales

__device__ __forceinline__ uint pack4_fp8(float a, float b, float c, float d) {
    uint r = 0;
    r = __builtin_amdgcn_cvt_pk_fp8_f32(a, b, r, false);
    r = __builtin_amdgcn_cvt_pk_fp8_f32(c, d, r, true);
    return r;
}
// fp4 e2m1 encode: grid {0,0.5,1,1.5,2,3,4,6}, nearest; input |x|<=4 here
__device__ __forceinline__ uint enc_fp4(float x) {
    float a = fabsf(x);
    uint idx = (a < 0.25f) ? 0u : (a < 0.75f) ? 1u : (a < 1.25f) ? 2u :
               (a < 1.75f) ? 3u : (a < 2.5f)  ? 4u : (a < 3.5f)  ? 5u :
               (a < 5.0f)  ? 6u : 7u;
    return idx | ((x < 0.f) ? 8u : 0u);
}
__device__ __forceinline__ void gload_lds16(const void* g, void* l) {
    __builtin_amdgcn_global_load_lds(
        (const __attribute__((address_space(1))) void*)g,
        (__attribute__((address_space(3))) void*)l, 16, 0, 0);
}

// ---- prep: E -> fp4 codebook (x4096) + scaled/biased norms + zero loss -----
__global__ __launch_bounds__(256) void vq_prep(const float* __restrict__ E,
                                               unsigned char* __restrict__ E4,
                                               float* __restrict__ enS,
                                               float* __restrict__ lossAcc) {
    int id = blockIdx.x * 256 + threadIdx.x;      // 65536 = 1024 codes * 64 f4
    if (id == 0) lossAcc[0] = 0.f;
    int code = id >> 6, c4 = id & 63;
    float4 v = *reinterpret_cast<const float4*>(E + (size_t)code * DIM + c4 * 4);
    uint n0 = enc_fp4(v.x * ESCALE4), n1 = enc_fp4(v.y * ESCALE4);
    uint n2 = enc_fp4(v.z * ESCALE4), n3 = enc_fp4(v.w * ESCALE4);
    uint hw = (n0 | (n1 << 4)) | ((n2 | (n3 << 4)) << 8);
    *reinterpret_cast<unsigned short*>(E4 + (size_t)code * 128 + c4 * 2) =
        (unsigned short)hw;

    float s = v.x * v.x + v.y * v.y + v.z * v.z + v.w * v.w;
    #pragma unroll
    for (int m = 32; m >= 1; m >>= 1) s += __shfl_down(s, m, 64);
    if (c4 == 0) enS[code] = s * 32768.0f + BIAS;
}

// ---- fused main (r12 structure + low-pressure per-n-pair fold) -------------
// Block: 256 thr = 4 waves, 128 rows (wave w: rows w*32..+31, m=2).
// Grid 512 -> 2 blocks/CU, 8 waves/CU. B: 8 tiles of 128 codes x 256 K fp4
// (16KB), double-buffered; per tile: __syncthreads -> stage(t+1) -> compute.
// Inner loop folds per n-PAIR: live acc = 16 VGPR -> total ~100 VGPR,
// fits the (256,2) 128-cap WITHOUT spill (r12 spilled: WRITE 88-90MB).
// MFMA: A = fp8(-16x), B = fp4(4096e) blgp=4, C-init = enS' so
// acc_out = 32768*(||e||^2 - 2x.e) + 16384; u32-packed argmin fold.
__global__ __launch_bounds__(256, 2) void vq_main(const float* __restrict__ X,
                                                  const unsigned char* __restrict__ E4,
                                                  const float* __restrict__ enS,
                                                  const float* __restrict__ E,
                                                  float* __restrict__ out,
                                                  float* __restrict__ lossAcc) {
    __shared__ __align__(16) unsigned char bsm[2 * 16384];  // 2 x 128-code tiles
    __shared__ float enSLds[1024];
    __shared__ int   bcLds[128];
    __shared__ float lossSh;

    const int tid = threadIdx.x;
    const int lane = tid & 63;
    const int w = tid >> 6;          // wave 0..3
    const int cl = lane & 15;
    const int kq = lane >> 4;
    const int row0 = blockIdx.x * 128;
    const int key = (cl & 7) << 4;   // read-side XOR swizzle

    auto stageB = [&](int tile, int buf) {
        unsigned char* dst = bsm + buf * 16384;
        const unsigned char* src = E4 + (size_t)(tile * 128) * 128;
        #pragma unroll
        for (int j = 0; j < 4; ++j) {
            int o = j * 4096 + tid * 16;             // linear LDS dest
            int rr = o >> 7;                         // code row in tile (0..127)
            int cb = (o & 127) ^ ((rr & 7) << 4);    // pre-swizzled source (rule 21)
            gload_lds16(src + rr * 128 + cb, dst + o);
        }
    };

    stageB(0, 0);                    // issue first tile ASAP (oldest vmem)

    // enS -> LDS (1024 f32; one float4 per thread)
    reinterpret_cast<f32x4*>(enSLds)[tid] =
        reinterpret_cast<const f32x4*>(enS)[tid];
    if (tid == 0) lossSh = 0.f;

    // ---- A phase: global -> fp8(-x) regs (m=2, K=128 frags) + x^2 partial --
    i32x8 aF[2][2];
    float xsum = 0.f;
    #pragma unroll
    for (int m = 0; m < 2; ++m) {
        const float* rp = X + (size_t)(row0 + w * 32 + m * 16 + cl) * DIM;
        #pragma unroll
        for (int ks = 0; ks < 2; ++ks) {
            const float* p = rp + ks * 128 + kq * 32;
            uint u[8];
            #pragma unroll
            for (int q = 0; q < 8; ++q) {
                float4 v = *reinterpret_cast<const float4*>(p + q * 4);
                u[q] = pack4_fp8(v.x * XSCALE, v.y * XSCALE,
                                 v.z * XSCALE, v.w * XSCALE);
                xsum = fmaf(v.x, v.x, xsum); xsum = fmaf(v.y, v.y, xsum);
                xsum = fmaf(v.z, v.z, xsum); xsum = fmaf(v.w, v.w, xsum);
            }
            i32x8 f = {(int)u[0], (int)u[1], (int)u[2], (int)u[3],
                       (int)u[4], (int)u[5], (int)u[6], (int)u[7]};
            aF[m][ks] = f;
        }
    }

    uint best[2][4];
    #pragma unroll
    for (int m = 0; m < 2; ++m)
        #pragma unroll
        for (int rr = 0; rr < 4; ++rr) best[m][rr] = 0xFFFFFFFFu;

    for (int t = 0; t < 8; ++t) {
        __syncthreads();                 // stage(t) + (t==0: enSLds) visible
        if (t < 7) stageB(t + 1, (t + 1) & 1);   // writer -> other buffer

        const unsigned char* bb = bsm + (t & 1) * 16384;

        __builtin_amdgcn_s_setprio(1);
        #pragma unroll
        for (int np = 0; np < 4; ++np) {
            const int n0 = np * 2, n1 = np * 2 + 1;
            float en0 = enSLds[t * 128 + n0 * 16 + cl];
            float en1 = enSLds[t * 128 + n1 * 16 + cl];
            f32x4 a00 = {en0, en0, en0, en0};
            f32x4 a01 = {en1, en1, en1, en1};
            f32x4 a10 = a00, a11 = a01;
            const unsigned char* rb0 = bb + (size_t)(n0 * 16 + cl) * 128;
            const unsigned char* rb1 = bb + (size_t)(n1 * 16 + cl) * 128;
            #pragma unroll
            for (int ks = 0; ks < 2; ++ks) {
                int l0 = (ks * 64 + kq * 16) ^ key;
                i32x4 lo0 = *reinterpret_cast<const i32x4*>(rb0 + l0);
                i32x4 lo1 = *reinterpret_cast<const i32x4*>(rb1 + l0);
                i32x8 bf0 = __builtin_shufflevector(lo0, lo0, 0, 1, 2, 3, 0, 1, 2, 3);
                i32x8 bf1 = __builtin_shufflevector(lo1, lo1, 0, 1, 2, 3, 0, 1, 2, 3);
                a00 = __builtin_amdgcn_mfma_scale_f32_16x16x128_f8f6f4(
                    aF[0][ks], bf0, a00, 0, 4, 0, SCALE1, 0, SCALE1);
                a10 = __builtin_amdgcn_mfma_scale_f32_16x16x128_f8f6f4(
                    aF[1][ks], bf0, a10, 0, 4, 0, SCALE1, 0, SCALE1);
                a01 = __builtin_amdgcn_mfma_scale_f32_16x16x128_f8f6f4(
                    aF[0][ks], bf1, a01, 0, 4, 0, SCALE1, 0, SCALE1);
                a11 = __builtin_amdgcn_mfma_scale_f32_16x16x128_f8f6f4(
                    aF[1][ks], bf1, a11, 0, 4, 0, SCALE1, 0, SCALE1);
            }
            // u32-packed fold (codes ascend -> min keeps first occurrence)
            uint c0 = (uint)(t * 128 + n0 * 16 + cl);
            uint c1 = (uint)(t * 128 + n1 * 16 + cl);
            #pragma unroll
            for (int rr = 0; rr < 4; ++rr) {
                best[0][rr] = min(best[0][rr],
                                  (__float_as_uint(a00[rr]) & 0xFFFFFC00u) | c0);
                best[0][rr] = min(best[0][rr],
                                  (__float_as_uint(a01[rr]) & 0xFFFFFC00u) | c1);
                best[1][rr] = min(best[1][rr],
                                  (__float_as_uint(a10[rr]) & 0xFFFFFC00u) | c0);
                best[1][rr] = min(best[1][rr],
                                  (__float_as_uint(a11[rr]) & 0xFFFFFC00u) | c1);
            }
        }
        __builtin_amdgcn_s_setprio(0);
    }

    // ---- epilogue: cross-cl reduce; C-row = m*16 + kq*4 + rr (m89 layout) --
    float minsum = 0.f;
    #pragma unroll
    for (int m = 0; m < 2; ++m)
        #pragma unroll
        for (int rr = 0; rr < 4; ++rr) {
            uint v = best[m][rr];
            #pragma unroll
            for (int mask = 1; mask < 16; mask <<= 1)
                v = min(v, (uint)__shfl_xor((int)v, mask, 64));
            if (cl == 0) {
                int row_l = w * 32 + m * 16 + kq * 4 + rr;
                bcLds[row_l] = (int)(v & 1023u);
                minsum += __uint_as_float(v & 0xFFFFFC00u) - BIAS;
            }
        }
    // loss partial: every thread's x^2 + (cl==0 lanes') scaled min-scores
    float v2 = xsum + ((cl == 0) ? minsum * UNSCALE : 0.f);
    #pragma unroll
    for (int mask = 1; mask < 64; mask <<= 1) v2 += __shfl_xor(v2, mask, 64);
    if (lane == 0) atomicAdd(&lossSh, v2);
    __syncthreads();                          // bcLds + lossSh ready

    // ---- out[row] = E[bc[row]] (== x + (q-x) to ~3e-7), streaming ----------
    #pragma unroll 4
    for (int i = 0; i < 32; ++i) {
        int g = i * 256 + tid;                // 8192 f4 = 128 rows x 64
        int rr = g >> 6, c4 = g & 63;
        int code = bcLds[rr];
        f32x4 q = *reinterpret_cast<const f32x4*>(E + (size_t)code * DIM + c4 * 4);
        __builtin_nontemporal_store(q,
            reinterpret_cast<f32x4*>(out + (size_t)(row0 + rr) * DIM + c4 * 4));
    }
    if (tid == 0) atomicAdd(lossAcc, lossSh);
}

__global__ void vq_finalize(const float* __restrict__ lossAcc,
                            float* __restrict__ out) {
    out[(size_t)N_ROWS * DIM] = 1.25f * lossAcc[0] / (float)((size_t)N_ROWS * DIM);
}

extern "C" void kernel_launch(void* const* d_in, const int* in_sizes, int n_in,
                              void* d_out, int out_size, void* d_ws, size_t ws_size,
                              hipStream_t stream) {
    const float* X = (const float*)d_in[0];
    const float* E = (const float*)d_in[1];
    float* out = (float*)d_out;

    char* ws = (char*)d_ws;
    float* lossAcc = (float*)(ws + WS_LOSS_OFF);
    float* enS = (float*)(ws + WS_ENS_OFF);
    unsigned char* E4 = (unsigned char*)(ws + WS_E4_OFF);

    vq_prep<<<256, 256, 0, stream>>>(E, E4, enS, lossAcc);
    vq_main<<<N_ROWS / 128, 256, 0, stream>>>(X, E4, enS, E, out, lossAcc);
    vq_finalize<<<1, 1, 0, stream>>>(lossAcc, out);
}